// Round 9
// baseline (755.241 us; speedup 1.0000x reference)
//
#include <hip/hip_runtime.h>

// ---------------------------------------------------------------------------
// SlotAttention forward, MI355X. B=64,S=16,F=4096,D=512,H=2048,3 iters.
// R9: R8 structure + two full-grid prologue-fusions (no grid shrinking):
//   (1) ln_mlp1: LN_mlp computed per-block into LDS inside the MLP1 GEMM,
//   (2) gru_gemm: upd_fin (Upart reduce + 1/fsum scale) as GRU prologue.
// Numerics bit-identical to R8. 6 launches/iter (was 8).
// ---------------------------------------------------------------------------

typedef __bf16 bf16x8 __attribute__((ext_vector_type(8)));
typedef float  f32x4  __attribute__((ext_vector_type(4)));

#define DEV static __device__ __forceinline__

DEV float bf2f_lo(unsigned int u) { union { unsigned int i; float f; } v; v.i = u << 16; return v.f; }
DEV unsigned short f2bf(float f) {
  union { float f; unsigned int i; } v; v.f = f;
  return (unsigned short)((v.i + 0x7FFFu + ((v.i >> 16) & 1u)) >> 16);
}

// ---------------------------------------------------------------------------
// LayerNorm rows of 512 (one wave per row). fp32 in, bf16 out (+opt fp32).
// ---------------------------------------------------------------------------
template<int OUTF>
__global__ __launch_bounds__(256) void ln512_kernel(
    const float* __restrict__ X, const float* __restrict__ g,
    const float* __restrict__ b, unsigned short* __restrict__ Yb,
    float* __restrict__ Yf, int R) {
  int wave = (blockIdx.x << 2) | (threadIdx.x >> 6);
  int lane = threadIdx.x & 63;
  if (wave >= R) return;
  const float4* xp = reinterpret_cast<const float4*>(X + (size_t)wave * 512);
  float4 x0 = xp[lane * 2], x1 = xp[lane * 2 + 1];
  float xv[8] = {x0.x, x0.y, x0.z, x0.w, x1.x, x1.y, x1.z, x1.w};
  float s = 0.f, q = 0.f;
#pragma unroll
  for (int j = 0; j < 8; ++j) { s += xv[j]; q += xv[j] * xv[j]; }
#pragma unroll
  for (int off = 32; off; off >>= 1) { s += __shfl_xor(s, off); q += __shfl_xor(q, off); }
  float mu = s * (1.0f / 512.0f);
  float var = q * (1.0f / 512.0f) - mu * mu;
  float rstd = rsqrtf(var + 1e-5f);
  const float4* gp = reinterpret_cast<const float4*>(g);
  const float4* bp = reinterpret_cast<const float4*>(b);
  float4 g0 = gp[lane * 2], g1 = gp[lane * 2 + 1];
  float4 b0 = bp[lane * 2], b1 = bp[lane * 2 + 1];
  float gv[8] = {g0.x, g0.y, g0.z, g0.w, g1.x, g1.y, g1.z, g1.w};
  float bv[8] = {b0.x, b0.y, b0.z, b0.w, b1.x, b1.y, b1.z, b1.w};
  float y[8];
  unsigned short u[8];
#pragma unroll
  for (int j = 0; j < 8; ++j) { y[j] = (xv[j] - mu) * rstd * gv[j] + bv[j]; u[j] = f2bf(y[j]); }
  uint4 o = make_uint4(
      (unsigned)u[0] | ((unsigned)u[1] << 16), (unsigned)u[2] | ((unsigned)u[3] << 16),
      (unsigned)u[4] | ((unsigned)u[5] << 16), (unsigned)u[6] | ((unsigned)u[7] << 16));
  reinterpret_cast<uint4*>(Yb + (size_t)wave * 512)[lane] = o;
  if (OUTF) {
    float4* yf = reinterpret_cast<float4*>(Yf + (size_t)wave * 512);
    yf[lane * 2]     = make_float4(y[0], y[1], y[2], y[3]);
    yf[lane * 2 + 1] = make_float4(y[4], y[5], y[6], y[7]);
  }
}

// ---------------------------------------------------------------------------
// Merged setup: cvt w_ih/w_hh/w1/w2 + transpose-cvt wk/wq/wv. grid 6656.
// ---------------------------------------------------------------------------
__global__ __launch_bounds__(256) void prep_weights_kernel(
    const float* __restrict__ w_ih, const float* __restrict__ w_hh,
    const float* __restrict__ w1, const float* __restrict__ w2,
    const float* __restrict__ w_k, const float* __restrict__ w_q,
    const float* __restrict__ w_v,
    unsigned short* __restrict__ Wih, unsigned short* __restrict__ Whh,
    unsigned short* __restrict__ W1, unsigned short* __restrict__ W2,
    unsigned short* __restrict__ WkT, unsigned short* __restrict__ WqT,
    unsigned short* __restrict__ WvT) {
  int blk = blockIdx.x, tid = threadIdx.x;
  if (blk < 3584) {  // flat converts (float4 units)
    const float* src; unsigned short* dst; int base;
    if (blk < 768)       { src = w_ih; dst = Wih; base = blk; }
    else if (blk < 1536) { src = w_hh; dst = Whh; base = blk - 768; }
    else if (blk < 2560) { src = w1;   dst = W1;  base = blk - 1536; }
    else                 { src = w2;   dst = W2;  base = blk - 2560; }
    int i = base * 256 + tid;
    float4 v = reinterpret_cast<const float4*>(src)[i];
    unsigned int lo = (unsigned)f2bf(v.x) | ((unsigned)f2bf(v.y) << 16);
    unsigned int hi = (unsigned)f2bf(v.z) | ((unsigned)f2bf(v.w) << 16);
    reinterpret_cast<uint2*>(dst)[i] = make_uint2(lo, hi);
  } else {  // 512x512 transposes
    int rgn = (blk - 3584) >> 10, base = (blk - 3584) & 1023;
    const float* src = rgn == 0 ? w_k : rgn == 1 ? w_q : w_v;
    unsigned short* dst = rgn == 0 ? WkT : rgn == 1 ? WqT : WvT;
    int t2 = base * 256 + tid;
    int i = t2 >> 9, j = t2 & 511;
    dst[t2] = f2bf(src[j * 512 + i]);
  }
}

// ---------------------------------------------------------------------------
// NT bf16 MFMA GEMM, block 32m x 128n, 4 waves n-adjacent, wave 32x32.
// MODE 0: bf16 plain (setup composites).
// ---------------------------------------------------------------------------
template<int MODE>
__global__ __launch_bounds__(256) void gemm_nt(
    const unsigned short* __restrict__ A, const unsigned short* __restrict__ Bm,
    const float* __restrict__ bias, unsigned short* __restrict__ Cb,
    int M, int N, int K) {
  int lane = threadIdx.x & 63;
  int w = threadIdx.x >> 6;
  int m0 = blockIdx.y << 5;
  int n0 = (blockIdx.x << 7) + (w << 5);
  int lo = lane & 15, hi = lane >> 4;
  const unsigned short* Ap = A + (size_t)(m0 + lo) * K + (hi << 3);
  const unsigned short* Bp = Bm + (size_t)(n0 + lo) * K + (hi << 3);
  f32x4 acc[2][2];
#pragma unroll
  for (int i = 0; i < 2; ++i)
#pragma unroll
    for (int j = 0; j < 2; ++j) acc[i][j] = f32x4{0.f, 0.f, 0.f, 0.f};
#pragma unroll 2
  for (int kk = 0; kk < K; kk += 32) {
    bf16x8 a0 = *reinterpret_cast<const bf16x8*>(Ap + kk);
    bf16x8 a1 = *reinterpret_cast<const bf16x8*>(Ap + (size_t)16 * K + kk);
    bf16x8 b0 = *reinterpret_cast<const bf16x8*>(Bp + kk);
    bf16x8 b1 = *reinterpret_cast<const bf16x8*>(Bp + (size_t)16 * K + kk);
    acc[0][0] = __builtin_amdgcn_mfma_f32_16x16x32_bf16(a0, b0, acc[0][0], 0, 0, 0);
    acc[0][1] = __builtin_amdgcn_mfma_f32_16x16x32_bf16(a0, b1, acc[0][1], 0, 0, 0);
    acc[1][0] = __builtin_amdgcn_mfma_f32_16x16x32_bf16(a1, b0, acc[1][0], 0, 0, 0);
    acc[1][1] = __builtin_amdgcn_mfma_f32_16x16x32_bf16(a1, b1, acc[1][1], 0, 0, 0);
  }
#pragma unroll
  for (int i = 0; i < 2; ++i)
#pragma unroll
    for (int j = 0; j < 2; ++j) {
      int col = n0 + (j << 4) + lo;
#pragma unroll
      for (int r = 0; r < 4; ++r) {
        int row = m0 + (i << 4) + (hi << 2) + r;
        Cb[(size_t)row * N + col] = f2bf(acc[i][j][r]);
      }
    }
}

// ---------------------------------------------------------------------------
// NT bf16 GEMM, block 32m x 64n, 4 waves (2m x 2n), wave 16x32.
// MODE 0: bf16 plain. MODE 4: v + bias + res -> f32.
// ---------------------------------------------------------------------------
template<int MODE>
__global__ __launch_bounds__(256) void gemm_nt64(
    const unsigned short* __restrict__ A, const unsigned short* __restrict__ Bm,
    const float* __restrict__ bias, const float* __restrict__ res,
    float* __restrict__ Cf, unsigned short* __restrict__ Cb,
    int M, int N, int K) {
  int lane = threadIdx.x & 63;
  int w = threadIdx.x >> 6;
  int m0 = (blockIdx.y << 5) + ((w >> 1) << 4);
  int n0 = (blockIdx.x << 6) + ((w & 1) << 5);
  int lo = lane & 15, hi = lane >> 4;
  const unsigned short* Ap = A + (size_t)(m0 + lo) * K + (hi << 3);
  const unsigned short* Bp = Bm + (size_t)(n0 + lo) * K + (hi << 3);
  f32x4 acc[2];
  acc[0] = f32x4{0.f, 0.f, 0.f, 0.f};
  acc[1] = f32x4{0.f, 0.f, 0.f, 0.f};
#pragma unroll 2
  for (int kk = 0; kk < K; kk += 32) {
    bf16x8 a0 = *reinterpret_cast<const bf16x8*>(Ap + kk);
    bf16x8 b0 = *reinterpret_cast<const bf16x8*>(Bp + kk);
    bf16x8 b1 = *reinterpret_cast<const bf16x8*>(Bp + (size_t)16 * K + kk);
    acc[0] = __builtin_amdgcn_mfma_f32_16x16x32_bf16(a0, b0, acc[0], 0, 0, 0);
    acc[1] = __builtin_amdgcn_mfma_f32_16x16x32_bf16(a0, b1, acc[1], 0, 0, 0);
  }
#pragma unroll
  for (int j = 0; j < 2; ++j) {
    int col = n0 + (j << 4) + lo;
    float bvv = (MODE == 4) ? bias[col] : 0.f;
#pragma unroll
    for (int r = 0; r < 4; ++r) {
      int row = m0 + (hi << 2) + r;
      float v = acc[j][r];
      if (MODE == 0) Cb[(size_t)row * N + col] = f2bf(v);
      else Cf[(size_t)row * N + col] = v + bvv + res[(size_t)row * N + col];
    }
  }
}

// ---------------------------------------------------------------------------
// Fused attention (R5-proven, 128 thr / 2 waves): per block (b, 256-f group),
// loop 8 chunks of 32 f: stage f_norm[32f][512d] in LDS (row stride 514 u16),
// dots MFMA -> softmax over s (shfl) -> attn to LDS -> PV MFMA accumulate.
// ---------------------------------------------------------------------------
__global__ __launch_bounds__(128) void fused_attn_kernel(
    const unsigned short* __restrict__ Qp,   // [B,16,512] bf16
    const unsigned short* __restrict__ Fn,   // [B,4096,512] bf16
    float* __restrict__ Upart,               // [B,16,16,512]
    float* __restrict__ fsumP,               // [B,32,16]
    float* __restrict__ attn_out) {          // [B,16,4096] fp32 or null
  __shared__ unsigned short tile[32 * 514];     // 32896 B
  __shared__ unsigned short attn_lds[16 * 34];  // 1088 B
  int b = blockIdx.y, g = blockIdx.x;
  int t = threadIdx.x;
  int w = t >> 6, lane = t & 63;
  int lo = lane & 15, hi = lane >> 4;
  unsigned int* tile32 = reinterpret_cast<unsigned int*>(tile);

  const unsigned short* qa = Qp + ((size_t)b * 16 + lo) * 512 + (hi << 3);
  const unsigned short* gstage = Fn + ((size_t)b * 4096 + g * 256) * 512;

  f32x4 uacc[16];
#pragma unroll
  for (int s = 0; s < 16; ++s) uacc[s] = f32x4{0.f, 0.f, 0.f, 0.f};
  float fs[4] = {0.f, 0.f, 0.f, 0.f};

  const float scale = 0.04419417382415922f;  // 512^-0.5

  {
    uint4 nx[16];
#pragma unroll
    for (int k = 0; k < 16; ++k)
      nx[k] = *reinterpret_cast<const uint4*>(gstage + (size_t)t * 8 + k * 1024);
#pragma unroll
    for (int k = 0; k < 16; ++k) {
      unsigned int* p32 = tile32 + (k * 2 + w) * 257 + lane * 4;
      p32[0] = nx[k].x; p32[1] = nx[k].y; p32[2] = nx[k].z; p32[3] = nx[k].w;
    }
  }
  __syncthreads();

  for (int c = 0; c < 8; ++c) {
    uint4 nx[16];
    if (c < 7) {
      const unsigned short* src = gstage + (size_t)(c + 1) * 16384;
#pragma unroll
      for (int k = 0; k < 16; ++k)
        nx[k] = *reinterpret_cast<const uint4*>(src + (size_t)t * 8 + k * 1024);
    }
    // --- dots ---
    f32x4 dacc = {0.f, 0.f, 0.f, 0.f};
#pragma unroll
    for (int ks = 0; ks < 16; ++ks) {
      const unsigned int* bp32 = tile32 + (w * 16 + lo) * 257 + ks * 16 + (hi << 2);
      union { unsigned int u[4]; bf16x8 v; } bf;
      bf.u[0] = bp32[0]; bf.u[1] = bp32[1]; bf.u[2] = bp32[2]; bf.u[3] = bp32[3];
      bf16x8 a = *reinterpret_cast<const bf16x8*>(qa + ks * 32);
      dacc = __builtin_amdgcn_mfma_f32_16x16x32_bf16(a, bf.v, dacc, 0, 0, 0);
    }
    // --- softmax over s ---
    float d4[4], mx = -3.4e38f;
#pragma unroll
    for (int r = 0; r < 4; ++r) { d4[r] = dacc[r] * scale; mx = fmaxf(mx, d4[r]); }
    mx = fmaxf(mx, __shfl_xor(mx, 16));
    mx = fmaxf(mx, __shfl_xor(mx, 32));
    float e4[4], ss = 0.f;
#pragma unroll
    for (int r = 0; r < 4; ++r) { e4[r] = __expf(d4[r] - mx); ss += e4[r]; }
    ss += __shfl_xor(ss, 16);
    ss += __shfl_xor(ss, 32);
    float inv = 1.f / ss;
    float cs[4];
#pragma unroll
    for (int r = 0; r < 4; ++r) {
      float p = e4[r] * inv;  // pre_norm_attn
      if (attn_out)
        attn_out[((size_t)b * 16 + (hi << 2) + r) * 4096 + g * 256 + c * 32 + (w << 4) + lo] = p;
      unsigned short uu = f2bf(p + 1e-8f);
      attn_lds[((hi << 2) + r) * 34 + (w << 4) + lo] = uu;
      cs[r] = bf2f_lo(uu);  // rounded -> consistent fsum
    }
#pragma unroll
    for (int m = 1; m < 16; m <<= 1) {
#pragma unroll
      for (int r = 0; r < 4; ++r) cs[r] += __shfl_xor(cs[r], m);
    }
#pragma unroll
    for (int r = 0; r < 4; ++r) fs[r] += cs[r];  // valid on lo==0 lanes
    __syncthreads();
    // --- PV ---
    {
      const unsigned int* ap32 = reinterpret_cast<const unsigned int*>(attn_lds) + lo * 17 + (hi << 2);
      union { unsigned int u[4]; bf16x8 v; } paf;
      paf.u[0] = ap32[0]; paf.u[1] = ap32[1]; paf.u[2] = ap32[2]; paf.u[3] = ap32[3];
#pragma unroll
      for (int sub = 0; sub < 16; ++sub) {
        int dcol = (w << 8) + (sub << 4) + lo;
        union { unsigned short u[8]; bf16x8 v; } pbf;
#pragma unroll
        for (int j = 0; j < 8; ++j)
          pbf.u[j] = tile[((hi << 3) + j) * 514 + dcol];
        uacc[sub] = __builtin_amdgcn_mfma_f32_16x16x32_bf16(paf.v, pbf.v, uacc[sub], 0, 0, 0);
      }
    }
    __syncthreads();
    if (c < 7) {
#pragma unroll
      for (int k = 0; k < 16; ++k) {
        unsigned int* p32 = tile32 + (k * 2 + w) * 257 + lane * 4;
        p32[0] = nx[k].x; p32[1] = nx[k].y; p32[2] = nx[k].z; p32[3] = nx[k].w;
      }
      __syncthreads();
    }
  }
#pragma unroll
  for (int sub = 0; sub < 16; ++sub) {
#pragma unroll
    for (int r = 0; r < 4; ++r)
      Upart[((size_t)(b * 16 + g) * 16 + (hi << 2) + r) * 512 + (w << 8) + (sub << 4) + lo] = uacc[sub][r];
  }
  if (lo == 0) {
#pragma unroll
    for (int r = 0; r < 4; ++r)
      fsumP[((size_t)(b * 16 + g) * 2 + w) * 16 + (hi << 2) + r] = fs[r];
  }
}

// ---------------------------------------------------------------------------
// Fused upd-finalize + gi/gh GEMMs + GRU. grid (4, 64); blockIdx.y = batch b.
// Prologue (replaces upd_fin): thread t reduces Upart[b,:,s,dchunk..+31]
// (s = t&15, dchunk = (t>>4)*32; same order as old upd_fin), scales by
// 1/fsum (redundant per-thread, same order), writes bf16 to LDS rows [16]
// with u32 stride 261 (odd -> 2-way banks on frag reads = free).
// ---------------------------------------------------------------------------
__global__ __launch_bounds__(256) void gru_gemm_kernel(
    const float* __restrict__ Upart,         // [B,16,16,512]
    const float* __restrict__ fsumP,         // [B,32,16]
    const unsigned short* __restrict__ As,   // s_n bf16 [1024,512]
    const unsigned short* __restrict__ Wc2,  // [1536,512] (wih@wv)
    const unsigned short* __restrict__ Whh,  // [1536,512]
    const float* __restrict__ b_ih, const float* __restrict__ b_hh,
    const float* __restrict__ snf,           // s_n fp32
    float* __restrict__ hout) {              // slots_c fp32
  __shared__ unsigned int au_lds[16 * 261];  // 16.7 KB
  int b = blockIdx.y;
  int t = threadIdx.x;
  // ---- prologue: updp rows for batch b -> LDS ----
  {
    int s = t & 15;
    int dchunk = (t >> 4) << 5;  // 0..480
    float fsum = 0.f;
#pragma unroll
    for (int i = 0; i < 32; ++i) fsum += fsumP[(size_t)b * 512 + i * 16 + s];
    float inv = 1.f / fsum;
    const float* p = Upart + (size_t)b * 131072 + s * 512 + dchunk;
#pragma unroll
    for (int q = 0; q < 8; ++q) {
      float4 acc = make_float4(0.f, 0.f, 0.f, 0.f);
#pragma unroll
      for (int g = 0; g < 16; ++g) {
        float4 v = *reinterpret_cast<const float4*>(p + (size_t)g * 8192 + q * 4);
        acc.x += v.x; acc.y += v.y; acc.z += v.z; acc.w += v.w;
      }
      unsigned int w0 = (unsigned)f2bf(acc.x * inv) | ((unsigned)f2bf(acc.y * inv) << 16);
      unsigned int w1 = (unsigned)f2bf(acc.z * inv) | ((unsigned)f2bf(acc.w * inv) << 16);
      unsigned int* dst = au_lds + s * 261 + ((dchunk + q * 4) >> 1);
      dst[0] = w0; dst[1] = w1;
    }
  }
  __syncthreads();
  // ---- GEMMs + GRU (A for gi from LDS; rest as before) ----
  int lane = t & 63, w = t >> 6;
  int lo = lane & 15, hi = lane >> 4;
  int m0 = b << 4;
  int cw = (blockIdx.x << 7) + (w << 5);
  const unsigned int* aup32 = au_lds + lo * 261 + (hi << 2);
  const unsigned short* asp = As + (size_t)(m0 + lo) * 512 + (hi << 3);
  const unsigned short* bc[2][3];
  const unsigned short* bh[2][3];
#pragma unroll
  for (int jt = 0; jt < 2; ++jt)
#pragma unroll
    for (int gt = 0; gt < 3; ++gt) {
      size_t rowoff = (size_t)(cw + jt * 16 + gt * 512 + lo) * 512 + (hi << 3);
      bc[jt][gt] = Wc2 + rowoff;
      bh[jt][gt] = Whh + rowoff;
    }
  f32x4 gi[2][3], gh[2][3];
#pragma unroll
  for (int jt = 0; jt < 2; ++jt)
#pragma unroll
    for (int gt = 0; gt < 3; ++gt) {
      gi[jt][gt] = f32x4{0.f, 0.f, 0.f, 0.f};
      gh[jt][gt] = f32x4{0.f, 0.f, 0.f, 0.f};
    }
  for (int kk = 0; kk < 512; kk += 32) {
    union { unsigned int u[4]; bf16x8 v; } au;
    const unsigned int* ap = aup32 + (kk >> 1);
    au.u[0] = ap[0]; au.u[1] = ap[1]; au.u[2] = ap[2]; au.u[3] = ap[3];
    bf16x8 as_ = *reinterpret_cast<const bf16x8*>(asp + kk);
#pragma unroll
    for (int jt = 0; jt < 2; ++jt)
#pragma unroll
      for (int gt = 0; gt < 3; ++gt) {
        bf16x8 wc = *reinterpret_cast<const bf16x8*>(bc[jt][gt] + kk);
        bf16x8 wh = *reinterpret_cast<const bf16x8*>(bh[jt][gt] + kk);
        gi[jt][gt] = __builtin_amdgcn_mfma_f32_16x16x32_bf16(au.v, wc, gi[jt][gt], 0, 0, 0);
        gh[jt][gt] = __builtin_amdgcn_mfma_f32_16x16x32_bf16(as_, wh, gh[jt][gt], 0, 0, 0);
      }
  }
#pragma unroll
  for (int jt = 0; jt < 2; ++jt) {
    int col = cw + (jt << 4) + lo;
    float bir = b_ih[col], biz = b_ih[col + 512], bin = b_ih[col + 1024];
    float bhr = b_hh[col], bhz = b_hh[col + 512], bhn = b_hh[col + 1024];
#pragma unroll
    for (int r = 0; r < 4; ++r) {
      int row = m0 + (hi << 2) + r;
      float rr = (gi[jt][0][r] + bir) + (gh[jt][0][r] + bhr);
      float zz = (gi[jt][1][r] + biz) + (gh[jt][1][r] + bhz);
      float rg = 1.f / (1.f + __expf(-rr));
      float zg = 1.f / (1.f + __expf(-zz));
      float a = (gi[jt][2][r] + bin) + rg * (gh[jt][2][r] + bhn);
      float ee = __expf(-2.f * fabsf(a));
      float nt = (1.f - ee) / (1.f + ee);
      float n = copysignf(nt, a);
      float hp = snf[(size_t)row * 512 + col];
      hout[(size_t)row * 512 + col] = (1.f - zg) * n + zg * hp;
    }
  }
}

// ---------------------------------------------------------------------------
// Fused LN_mlp + MLP1 GEMM. grid (16, 32) — full 512 blocks, 256 thr.
// Prologue: LN the block's 32 slots_c rows into LDS (u32 stride 261).
// GEMM: 32m x 128n tile vs W1, relu+bias -> hm bf16. Same math as before.
// ---------------------------------------------------------------------------
__global__ __launch_bounds__(256) void ln_mlp1_kernel(
    const float* __restrict__ X,             // slots_c [1024,512]
    const float* __restrict__ g, const float* __restrict__ bta,
    const unsigned short* __restrict__ W1,   // [2048,512]
    const float* __restrict__ b1,
    unsigned short* __restrict__ hm) {       // [1024,2048]
  __shared__ unsigned int lds[32 * 261];     // 33.4 KB
  int m0 = blockIdx.y << 5;
  int t = threadIdx.x, w = t >> 6, lane = t & 63;
  // ---- LN prologue: wave w does rows w+4p (ln512 pattern/order) ----
  {
    const float4* gp = reinterpret_cast<const float4*>(g) + lane * 2;
    const float4* bp = reinterpret_cast<const float4*>(bta) + lane * 2;
    float4 g0 = gp[0], g1 = gp[1], c0 = bp[0], c1 = bp[1];
    float gv[8] = {g0.x, g0.y, g0.z, g0.w, g1.x, g1.y, g1.z, g1.w};
    float bv[8] = {c0.x, c0.y, c0.z, c0.w, c1.x, c1.y, c1.z, c1.w};
#pragma unroll
    for (int p = 0; p < 8; ++p) {
      int r = (p << 2) | w;
      const float4* xp = reinterpret_cast<const float4*>(X + (size_t)(m0 + r) * 512) + lane * 2;
      float4 x0 = xp[0], x1 = xp[1];
      float xv[8] = {x0.x, x0.y, x0.z, x0.w, x1.x, x1.y, x1.z, x1.w};
      float s = 0.f, q = 0.f;
#pragma unroll
      for (int j = 0; j < 8; ++j) { s += xv[j]; q += xv[j] * xv[j]; }
#pragma unroll
      for (int off = 32; off; off >>= 1) { s += __shfl_xor(s, off); q += __shfl_xor(q, off); }
      float mu = s * (1.0f / 512.0f);
      float var = q * (1.0f / 512.0f) - mu * mu;
      float rstd = rsqrtf(var + 1e-5f);
      unsigned int pk[4];
#pragma unroll
      for (int j = 0; j < 4; ++j) {
        unsigned short u0 = f2bf((xv[2 * j] - mu) * rstd * gv[2 * j] + bv[2 * j]);
        unsigned short u1 = f2bf((xv[2 * j + 1] - mu) * rstd * gv[2 * j + 1] + bv[2 * j + 1]);
        pk[j] = (unsigned)u0 | ((unsigned)u1 << 16);
      }
      unsigned int* dst = lds + r * 261 + lane * 4;
      dst[0] = pk[0]; dst[1] = pk[1]; dst[2] = pk[2]; dst[3] = pk[3];
    }
  }
  __syncthreads();
  // ---- GEMM: A from LDS, B = W1 global ----
  int lo = lane & 15, hi = lane >> 4;
  int n0 = (blockIdx.x << 7) + (w << 5);
  const unsigned short* Bp = W1 + (size_t)(n0 + lo) * 512 + (hi << 3);
  f32x4 acc[2][2];
#pragma unroll
  for (int i = 0; i < 2; ++i)
#pragma unroll
    for (int j = 0; j < 2; ++j) acc[i][j] = f32x4{0.f, 0.f, 0.f, 0.f};
  const unsigned int* a0p = lds + lo * 261 + (hi << 2);
  const unsigned int* a1p = lds + (16 + lo) * 261 + (hi << 2);
#pragma unroll 2
  for (int kk = 0; kk < 512; kk += 32) {
    union { unsigned int u[4]; bf16x8 v; } a0, a1;
    const unsigned int* p0 = a0p + (kk >> 1);
    const unsigned int* p1 = a1p + (kk >> 1);
    a0.u[0] = p0[0]; a0.u[1] = p0[1]; a0.u[2] = p0[2]; a0.u[3] = p0[3];
    a1.u[0] = p1[0]; a1.u[1] = p1[1]; a1.u[2] = p1[2]; a1.u[3] = p1[3];
    bf16x8 b0 = *reinterpret_cast<const bf16x8*>(Bp + kk);
    bf16x8 b1 = *reinterpret_cast<const bf16x8*>(Bp + (size_t)16 * 512 + kk);
    acc[0][0] = __builtin_amdgcn_mfma_f32_16x16x32_bf16(a0.v, b0, acc[0][0], 0, 0, 0);
    acc[0][1] = __builtin_amdgcn_mfma_f32_16x16x32_bf16(a0.v, b1, acc[0][1], 0, 0, 0);
    acc[1][0] = __builtin_amdgcn_mfma_f32_16x16x32_bf16(a1.v, b0, acc[1][0], 0, 0, 0);
    acc[1][1] = __builtin_amdgcn_mfma_f32_16x16x32_bf16(a1.v, b1, acc[1][1], 0, 0, 0);
  }
#pragma unroll
  for (int i = 0; i < 2; ++i)
#pragma unroll
    for (int j = 0; j < 2; ++j) {
      int col = n0 + (j << 4) + lo;
      float bvv = b1[col];
#pragma unroll
      for (int r = 0; r < 4; ++r) {
        int row = m0 + (i << 4) + (hi << 2) + r;
        hm[(size_t)row * 2048 + col] = f2bf(fmaxf(acc[i][j][r] + bvv, 0.f));
      }
    }
}

// ---------------------------------------------------------------------------
extern "C" void kernel_launch(void* const* d_in, const int* in_sizes, int n_in,
                              void* d_out, int out_size, void* d_ws, size_t ws_size,
                              hipStream_t stream) {
  const float* slots_in  = (const float*)d_in[0];
  const float* features  = (const float*)d_in[1];
  const float* ln_feat_g = (const float*)d_in[2];
  const float* ln_feat_b = (const float*)d_in[3];
  const float* ln_slot_g = (const float*)d_in[4];
  const float* ln_slot_b = (const float*)d_in[5];
  const float* w_k  = (const float*)d_in[6];
  const float* w_v  = (const float*)d_in[7];
  const float* w_q  = (const float*)d_in[8];
  const float* w_ih = (const float*)d_in[9];
  const float* w_hh = (const float*)d_in[10];
  const float* b_ih = (const float*)d_in[11];
  const float* b_hh = (const float*)d_in[12];
  const float* mlp_ln_g = (const float*)d_in[13];
  const float* mlp_ln_b = (const float*)d_in[14];
  const float* w1 = (const float*)d_in[15];
  const float* b1 = (const float*)d_in[16];
  const float* w2 = (const float*)d_in[17];
  const float* b2 = (const float*)d_in[18];

  char* ws = (char*)d_ws;
  size_t off = 0;
  auto alloc = [&](size_t bytes) {
    char* p = ws + off;
    off += (bytes + 255) & ~(size_t)255;
    return p;
  };
  unsigned short* f_norm  = (unsigned short*)alloc((size_t)64 * 4096 * 512 * 2);  // 256MB
  unsigned short* qp_bf   = (unsigned short*)alloc(1024 * 512 * 2);
  float*          s_n_f   = (float*)alloc(1024 * 512 * 4);
  unsigned short* s_n_bf  = (unsigned short*)alloc(1024 * 512 * 2);
  float*          fsumP   = (float*)alloc(64 * 32 * 16 * 4);
  float*          Upart   = (float*)alloc((size_t)64 * 16 * 16 * 512 * 4);        // 32MB
  float*          slots_c = (float*)alloc(1024 * 512 * 4);
  unsigned short* hm_bf   = (unsigned short*)alloc((size_t)1024 * 2048 * 2);
  unsigned short* Wqk_bf  = (unsigned short*)alloc(512 * 512 * 2);   // wk^T wq
  unsigned short* Wih_bf  = (unsigned short*)alloc(1536 * 512 * 2);
  unsigned short* Whh_bf  = (unsigned short*)alloc(1536 * 512 * 2);
  unsigned short* WkT_bf  = (unsigned short*)alloc(512 * 512 * 2);
  unsigned short* WqT_bf  = (unsigned short*)alloc(512 * 512 * 2);
  unsigned short* WvT_bf  = (unsigned short*)alloc(512 * 512 * 2);
  unsigned short* Wc2_bf  = (unsigned short*)alloc(1536 * 512 * 2);  // wih@wv
  unsigned short* W1_bf   = (unsigned short*)alloc((size_t)2048 * 512 * 2);
  unsigned short* W2_bf   = (unsigned short*)alloc((size_t)512 * 2048 * 2);

  float* out_slots = (float*)d_out;               // [64,16,512]
  float* out_attn  = out_slots + 1024 * 512;      // [64,16,4096]

  // --- setup ---
  prep_weights_kernel<<<dim3(6656), dim3(256), 0, stream>>>(
      w_ih, w_hh, w1, w2, w_k, w_q, w_v,
      Wih_bf, Whh_bf, W1_bf, W2_bf, WkT_bf, WqT_bf, WvT_bf);
  gemm_nt<0><<<dim3(4, 16), dim3(256), 0, stream>>>(
      WkT_bf, WqT_bf, nullptr, Wqk_bf, 512, 512, 512);
  gemm_nt<0><<<dim3(4, 48), dim3(256), 0, stream>>>(
      Wih_bf, WvT_bf, nullptr, Wc2_bf, 1536, 512, 512);
  // f_norm = LN(features) -> bf16 (single pass)
  ln512_kernel<0><<<dim3(65536), dim3(256), 0, stream>>>(
      features, ln_feat_g, ln_feat_b, f_norm, nullptr, 262144);

  for (int it = 0; it < 3; ++it) {
    const float* slots_src = (it == 0) ? slots_in : slots_c;
    // s_n = LN(slots)
    ln512_kernel<1><<<dim3(256), dim3(256), 0, stream>>>(
        slots_src, ln_slot_g, ln_slot_b, s_n_bf, s_n_f, 1024);
    // qp = s_n @ Wqk^T
    gemm_nt64<0><<<dim3(8, 32), dim3(256), 0, stream>>>(
        s_n_bf, Wqk_bf, nullptr, nullptr, nullptr, qp_bf, 1024, 512, 512);
    // fused dots+softmax+PV (single f_norm pass)
    fused_attn_kernel<<<dim3(16, 64), dim3(128), 0, stream>>>(
        qp_bf, f_norm, Upart, fsumP, (it == 2) ? out_attn : nullptr);
    // upd-finalize + gi/gh GEMMs + GRU -> slots_c
    gru_gemm_kernel<<<dim3(4, 64), dim3(256), 0, stream>>>(
        Upart, fsumP, s_n_bf, Wc2_bf, Whh_bf, b_ih, b_hh, s_n_f, slots_c);
    // LN_mlp + MLP1 fused (full 512-block grid)
    ln_mlp1_kernel<<<dim3(16, 32), dim3(256), 0, stream>>>(
        slots_c, mlp_ln_g, mlp_ln_b, W1_bf, b1, hm_bf);
    // MLP2 + residual
    float* slot_dst = (it == 2) ? out_slots : slots_c;
    gemm_nt64<4><<<dim3(8, 32), dim3(256), 0, stream>>>(
        hm_bf, W2_bf, b2, slots_c, slot_dst, nullptr, 1024, 512, 2048);
  }
  (void)in_sizes; (void)n_in; (void)out_size; (void)ws_size;
}

// Round 10
// 694.964 us; speedup vs baseline: 1.0867x; 1.0867x over previous
//
#include <hip/hip_runtime.h>

// ---------------------------------------------------------------------------
// SlotAttention forward, MI355X. B=64,S=16,F=4096,D=512,H=2048,3 iters.
// R10: exact R8 re-baseline (best measured 694.4us). R9's prologue-fusions
// reverted (post-mortem: +96MB redundant Upart reads + serialized prologues).
// Structure: R5 fused-attention + invf folded into upd_fin.
// ---------------------------------------------------------------------------

typedef __bf16 bf16x8 __attribute__((ext_vector_type(8)));
typedef float  f32x4  __attribute__((ext_vector_type(4)));

#define DEV static __device__ __forceinline__

DEV float bf2f_lo(unsigned int u) { union { unsigned int i; float f; } v; v.i = u << 16; return v.f; }
DEV unsigned short f2bf(float f) {
  union { float f; unsigned int i; } v; v.f = f;
  return (unsigned short)((v.i + 0x7FFFu + ((v.i >> 16) & 1u)) >> 16);
}

// ---------------------------------------------------------------------------
// LayerNorm rows of 512 (one wave per row). fp32 in, bf16 out (+opt fp32).
// ---------------------------------------------------------------------------
template<int OUTF>
__global__ __launch_bounds__(256) void ln512_kernel(
    const float* __restrict__ X, const float* __restrict__ g,
    const float* __restrict__ b, unsigned short* __restrict__ Yb,
    float* __restrict__ Yf, int R) {
  int wave = (blockIdx.x << 2) | (threadIdx.x >> 6);
  int lane = threadIdx.x & 63;
  if (wave >= R) return;
  const float4* xp = reinterpret_cast<const float4*>(X + (size_t)wave * 512);
  float4 x0 = xp[lane * 2], x1 = xp[lane * 2 + 1];
  float xv[8] = {x0.x, x0.y, x0.z, x0.w, x1.x, x1.y, x1.z, x1.w};
  float s = 0.f, q = 0.f;
#pragma unroll
  for (int j = 0; j < 8; ++j) { s += xv[j]; q += xv[j] * xv[j]; }
#pragma unroll
  for (int off = 32; off; off >>= 1) { s += __shfl_xor(s, off); q += __shfl_xor(q, off); }
  float mu = s * (1.0f / 512.0f);
  float var = q * (1.0f / 512.0f) - mu * mu;
  float rstd = rsqrtf(var + 1e-5f);
  const float4* gp = reinterpret_cast<const float4*>(g);
  const float4* bp = reinterpret_cast<const float4*>(b);
  float4 g0 = gp[lane * 2], g1 = gp[lane * 2 + 1];
  float4 b0 = bp[lane * 2], b1 = bp[lane * 2 + 1];
  float gv[8] = {g0.x, g0.y, g0.z, g0.w, g1.x, g1.y, g1.z, g1.w};
  float bv[8] = {b0.x, b0.y, b0.z, b0.w, b1.x, b1.y, b1.z, b1.w};
  float y[8];
  unsigned short u[8];
#pragma unroll
  for (int j = 0; j < 8; ++j) { y[j] = (xv[j] - mu) * rstd * gv[j] + bv[j]; u[j] = f2bf(y[j]); }
  uint4 o = make_uint4(
      (unsigned)u[0] | ((unsigned)u[1] << 16), (unsigned)u[2] | ((unsigned)u[3] << 16),
      (unsigned)u[4] | ((unsigned)u[5] << 16), (unsigned)u[6] | ((unsigned)u[7] << 16));
  reinterpret_cast<uint4*>(Yb + (size_t)wave * 512)[lane] = o;
  if (OUTF) {
    float4* yf = reinterpret_cast<float4*>(Yf + (size_t)wave * 512);
    yf[lane * 2]     = make_float4(y[0], y[1], y[2], y[3]);
    yf[lane * 2 + 1] = make_float4(y[4], y[5], y[6], y[7]);
  }
}

// ---------------------------------------------------------------------------
// Merged setup: cvt w_ih/w_hh/w1/w2 + transpose-cvt wk/wq/wv. grid 6656.
// ---------------------------------------------------------------------------
__global__ __launch_bounds__(256) void prep_weights_kernel(
    const float* __restrict__ w_ih, const float* __restrict__ w_hh,
    const float* __restrict__ w1, const float* __restrict__ w2,
    const float* __restrict__ w_k, const float* __restrict__ w_q,
    const float* __restrict__ w_v,
    unsigned short* __restrict__ Wih, unsigned short* __restrict__ Whh,
    unsigned short* __restrict__ W1, unsigned short* __restrict__ W2,
    unsigned short* __restrict__ WkT, unsigned short* __restrict__ WqT,
    unsigned short* __restrict__ WvT) {
  int blk = blockIdx.x, tid = threadIdx.x;
  if (blk < 3584) {  // flat converts (float4 units)
    const float* src; unsigned short* dst; int base;
    if (blk < 768)       { src = w_ih; dst = Wih; base = blk; }
    else if (blk < 1536) { src = w_hh; dst = Whh; base = blk - 768; }
    else if (blk < 2560) { src = w1;   dst = W1;  base = blk - 1536; }
    else                 { src = w2;   dst = W2;  base = blk - 2560; }
    int i = base * 256 + tid;
    float4 v = reinterpret_cast<const float4*>(src)[i];
    unsigned int lo = (unsigned)f2bf(v.x) | ((unsigned)f2bf(v.y) << 16);
    unsigned int hi = (unsigned)f2bf(v.z) | ((unsigned)f2bf(v.w) << 16);
    reinterpret_cast<uint2*>(dst)[i] = make_uint2(lo, hi);
  } else {  // 512x512 transposes
    int rgn = (blk - 3584) >> 10, base = (blk - 3584) & 1023;
    const float* src = rgn == 0 ? w_k : rgn == 1 ? w_q : w_v;
    unsigned short* dst = rgn == 0 ? WkT : rgn == 1 ? WqT : WvT;
    int t2 = base * 256 + tid;
    int i = t2 >> 9, j = t2 & 511;
    dst[t2] = f2bf(src[j * 512 + i]);
  }
}

// ---------------------------------------------------------------------------
// NT bf16 MFMA GEMM, block 32m x 128n, 4 waves n-adjacent, wave 32x32.
// MODE 0: bf16 plain. MODE 3: relu(v+bias)->bf16.
// ---------------------------------------------------------------------------
template<int MODE>
__global__ __launch_bounds__(256) void gemm_nt(
    const unsigned short* __restrict__ A, const unsigned short* __restrict__ Bm,
    const float* __restrict__ bias, unsigned short* __restrict__ Cb,
    int M, int N, int K) {
  int lane = threadIdx.x & 63;
  int w = threadIdx.x >> 6;
  int m0 = blockIdx.y << 5;
  int n0 = (blockIdx.x << 7) + (w << 5);
  int lo = lane & 15, hi = lane >> 4;
  const unsigned short* Ap = A + (size_t)(m0 + lo) * K + (hi << 3);
  const unsigned short* Bp = Bm + (size_t)(n0 + lo) * K + (hi << 3);
  f32x4 acc[2][2];
#pragma unroll
  for (int i = 0; i < 2; ++i)
#pragma unroll
    for (int j = 0; j < 2; ++j) acc[i][j] = f32x4{0.f, 0.f, 0.f, 0.f};
#pragma unroll 2
  for (int kk = 0; kk < K; kk += 32) {
    bf16x8 a0 = *reinterpret_cast<const bf16x8*>(Ap + kk);
    bf16x8 a1 = *reinterpret_cast<const bf16x8*>(Ap + (size_t)16 * K + kk);
    bf16x8 b0 = *reinterpret_cast<const bf16x8*>(Bp + kk);
    bf16x8 b1 = *reinterpret_cast<const bf16x8*>(Bp + (size_t)16 * K + kk);
    acc[0][0] = __builtin_amdgcn_mfma_f32_16x16x32_bf16(a0, b0, acc[0][0], 0, 0, 0);
    acc[0][1] = __builtin_amdgcn_mfma_f32_16x16x32_bf16(a0, b1, acc[0][1], 0, 0, 0);
    acc[1][0] = __builtin_amdgcn_mfma_f32_16x16x32_bf16(a1, b0, acc[1][0], 0, 0, 0);
    acc[1][1] = __builtin_amdgcn_mfma_f32_16x16x32_bf16(a1, b1, acc[1][1], 0, 0, 0);
  }
#pragma unroll
  for (int i = 0; i < 2; ++i)
#pragma unroll
    for (int j = 0; j < 2; ++j) {
      int col = n0 + (j << 4) + lo;
      float bvv = (MODE == 3) ? bias[col] : 0.f;
#pragma unroll
      for (int r = 0; r < 4; ++r) {
        int row = m0 + (i << 4) + (hi << 2) + r;
        float v = acc[i][j][r];
        if (MODE == 0) Cb[(size_t)row * N + col] = f2bf(v);
        else           Cb[(size_t)row * N + col] = f2bf(fmaxf(v + bvv, 0.f));
      }
    }
}

// ---------------------------------------------------------------------------
// NT bf16 GEMM, block 32m x 64n, 4 waves (2m x 2n), wave 16x32.
// MODE 0: bf16 plain. MODE 4: v + bias + res -> f32.
// ---------------------------------------------------------------------------
template<int MODE>
__global__ __launch_bounds__(256) void gemm_nt64(
    const unsigned short* __restrict__ A, const unsigned short* __restrict__ Bm,
    const float* __restrict__ bias, const float* __restrict__ res,
    float* __restrict__ Cf, unsigned short* __restrict__ Cb,
    int M, int N, int K) {
  int lane = threadIdx.x & 63;
  int w = threadIdx.x >> 6;
  int m0 = (blockIdx.y << 5) + ((w >> 1) << 4);
  int n0 = (blockIdx.x << 6) + ((w & 1) << 5);
  int lo = lane & 15, hi = lane >> 4;
  const unsigned short* Ap = A + (size_t)(m0 + lo) * K + (hi << 3);
  const unsigned short* Bp = Bm + (size_t)(n0 + lo) * K + (hi << 3);
  f32x4 acc[2];
  acc[0] = f32x4{0.f, 0.f, 0.f, 0.f};
  acc[1] = f32x4{0.f, 0.f, 0.f, 0.f};
#pragma unroll 2
  for (int kk = 0; kk < K; kk += 32) {
    bf16x8 a0 = *reinterpret_cast<const bf16x8*>(Ap + kk);
    bf16x8 b0 = *reinterpret_cast<const bf16x8*>(Bp + kk);
    bf16x8 b1 = *reinterpret_cast<const bf16x8*>(Bp + (size_t)16 * K + kk);
    acc[0] = __builtin_amdgcn_mfma_f32_16x16x32_bf16(a0, b0, acc[0], 0, 0, 0);
    acc[1] = __builtin_amdgcn_mfma_f32_16x16x32_bf16(a0, b1, acc[1], 0, 0, 0);
  }
#pragma unroll
  for (int j = 0; j < 2; ++j) {
    int col = n0 + (j << 4) + lo;
    float bvv = (MODE == 4) ? bias[col] : 0.f;
#pragma unroll
    for (int r = 0; r < 4; ++r) {
      int row = m0 + (hi << 2) + r;
      float v = acc[j][r];
      if (MODE == 0) Cb[(size_t)row * N + col] = f2bf(v);
      else Cf[(size_t)row * N + col] = v + bvv + res[(size_t)row * N + col];
    }
  }
}

// ---------------------------------------------------------------------------
// Fused attention (R5-proven, 128 thr / 2 waves): per block (b, 256-f group),
// loop 8 chunks of 32 f: stage f_norm[32f][512d] in LDS (row stride 514 u16),
// dots MFMA -> softmax over s (shfl) -> attn to LDS -> PV MFMA accumulate.
// ---------------------------------------------------------------------------
__global__ __launch_bounds__(128) void fused_attn_kernel(
    const unsigned short* __restrict__ Qp,   // [B,16,512] bf16
    const unsigned short* __restrict__ Fn,   // [B,4096,512] bf16
    float* __restrict__ Upart,               // [B,16,16,512]
    float* __restrict__ fsumP,               // [B,32,16]
    float* __restrict__ attn_out) {          // [B,16,4096] fp32 or null
  __shared__ unsigned short tile[32 * 514];     // 32896 B
  __shared__ unsigned short attn_lds[16 * 34];  // 1088 B
  int b = blockIdx.y, g = blockIdx.x;
  int t = threadIdx.x;
  int w = t >> 6, lane = t & 63;
  int lo = lane & 15, hi = lane >> 4;
  unsigned int* tile32 = reinterpret_cast<unsigned int*>(tile);

  const unsigned short* qa = Qp + ((size_t)b * 16 + lo) * 512 + (hi << 3);
  const unsigned short* gstage = Fn + ((size_t)b * 4096 + g * 256) * 512;

  f32x4 uacc[16];
#pragma unroll
  for (int s = 0; s < 16; ++s) uacc[s] = f32x4{0.f, 0.f, 0.f, 0.f};
  float fs[4] = {0.f, 0.f, 0.f, 0.f};

  const float scale = 0.04419417382415922f;  // 512^-0.5

  {
    uint4 nx[16];
#pragma unroll
    for (int k = 0; k < 16; ++k)
      nx[k] = *reinterpret_cast<const uint4*>(gstage + (size_t)t * 8 + k * 1024);
#pragma unroll
    for (int k = 0; k < 16; ++k) {
      unsigned int* p32 = tile32 + (k * 2 + w) * 257 + lane * 4;
      p32[0] = nx[k].x; p32[1] = nx[k].y; p32[2] = nx[k].z; p32[3] = nx[k].w;
    }
  }
  __syncthreads();

  for (int c = 0; c < 8; ++c) {
    uint4 nx[16];
    if (c < 7) {
      const unsigned short* src = gstage + (size_t)(c + 1) * 16384;
#pragma unroll
      for (int k = 0; k < 16; ++k)
        nx[k] = *reinterpret_cast<const uint4*>(src + (size_t)t * 8 + k * 1024);
    }
    // --- dots ---
    f32x4 dacc = {0.f, 0.f, 0.f, 0.f};
#pragma unroll
    for (int ks = 0; ks < 16; ++ks) {
      const unsigned int* bp32 = tile32 + (w * 16 + lo) * 257 + ks * 16 + (hi << 2);
      union { unsigned int u[4]; bf16x8 v; } bf;
      bf.u[0] = bp32[0]; bf.u[1] = bp32[1]; bf.u[2] = bp32[2]; bf.u[3] = bp32[3];
      bf16x8 a = *reinterpret_cast<const bf16x8*>(qa + ks * 32);
      dacc = __builtin_amdgcn_mfma_f32_16x16x32_bf16(a, bf.v, dacc, 0, 0, 0);
    }
    // --- softmax over s ---
    float d4[4], mx = -3.4e38f;
#pragma unroll
    for (int r = 0; r < 4; ++r) { d4[r] = dacc[r] * scale; mx = fmaxf(mx, d4[r]); }
    mx = fmaxf(mx, __shfl_xor(mx, 16));
    mx = fmaxf(mx, __shfl_xor(mx, 32));
    float e4[4], ss = 0.f;
#pragma unroll
    for (int r = 0; r < 4; ++r) { e4[r] = __expf(d4[r] - mx); ss += e4[r]; }
    ss += __shfl_xor(ss, 16);
    ss += __shfl_xor(ss, 32);
    float inv = 1.f / ss;
    float cs[4];
#pragma unroll
    for (int r = 0; r < 4; ++r) {
      float p = e4[r] * inv;  // pre_norm_attn
      if (attn_out)
        attn_out[((size_t)b * 16 + (hi << 2) + r) * 4096 + g * 256 + c * 32 + (w << 4) + lo] = p;
      unsigned short uu = f2bf(p + 1e-8f);
      attn_lds[((hi << 2) + r) * 34 + (w << 4) + lo] = uu;
      cs[r] = bf2f_lo(uu);  // rounded -> consistent fsum
    }
#pragma unroll
    for (int m = 1; m < 16; m <<= 1) {
#pragma unroll
      for (int r = 0; r < 4; ++r) cs[r] += __shfl_xor(cs[r], m);
    }
#pragma unroll
    for (int r = 0; r < 4; ++r) fs[r] += cs[r];  // valid on lo==0 lanes
    __syncthreads();
    // --- PV ---
    {
      const unsigned int* ap32 = reinterpret_cast<const unsigned int*>(attn_lds) + lo * 17 + (hi << 2);
      union { unsigned int u[4]; bf16x8 v; } paf;
      paf.u[0] = ap32[0]; paf.u[1] = ap32[1]; paf.u[2] = ap32[2]; paf.u[3] = ap32[3];
#pragma unroll
      for (int sub = 0; sub < 16; ++sub) {
        int dcol = (w << 8) + (sub << 4) + lo;
        union { unsigned short u[8]; bf16x8 v; } pbf;
#pragma unroll
        for (int j = 0; j < 8; ++j)
          pbf.u[j] = tile[((hi << 3) + j) * 514 + dcol];
        uacc[sub] = __builtin_amdgcn_mfma_f32_16x16x32_bf16(paf.v, pbf.v, uacc[sub], 0, 0, 0);
      }
    }
    __syncthreads();
    if (c < 7) {
#pragma unroll
      for (int k = 0; k < 16; ++k) {
        unsigned int* p32 = tile32 + (k * 2 + w) * 257 + lane * 4;
        p32[0] = nx[k].x; p32[1] = nx[k].y; p32[2] = nx[k].z; p32[3] = nx[k].w;
      }
      __syncthreads();
    }
  }
#pragma unroll
  for (int sub = 0; sub < 16; ++sub) {
#pragma unroll
    for (int r = 0; r < 4; ++r)
      Upart[((size_t)(b * 16 + g) * 16 + (hi << 2) + r) * 512 + (w << 8) + (sub << 4) + lo] = uacc[sub][r];
  }
  if (lo == 0) {
#pragma unroll
    for (int r = 0; r < 4; ++r)
      fsumP[((size_t)(b * 16 + g) * 2 + w) * 16 + (hi << 2) + r] = fs[r];
  }
}

// ---------------------------------------------------------------------------
// finalize: upd_bf[b,s,d] = f2bf( (sum_g Upart[b,g,s,d]) / (sum fsumP[b,:,s]) )
// grid 2048: block = one (b,s,d-half). invf computed redundantly (L2-hot).
// ---------------------------------------------------------------------------
__global__ __launch_bounds__(256) void upd_fin_kernel(
    const float* __restrict__ Upart, const float* __restrict__ fsumP,
    unsigned short* __restrict__ outb) {
  int blk = blockIdx.x;
  int b = blk >> 5;
  int s = (blk >> 1) & 15;
  int d = ((blk & 1) << 8) + threadIdx.x;
  float fsum = 0.f;
#pragma unroll
  for (int i = 0; i < 32; ++i) fsum += fsumP[(size_t)b * 512 + i * 16 + s];
  float inv = 1.f / fsum;
  const float* p = Upart + (size_t)b * 131072 + s * 512 + d;
  float acc = 0.f;
#pragma unroll
  for (int g = 0; g < 16; ++g) acc += p[(size_t)g * 8192];
  outb[((size_t)b * 16 + s) * 512 + d] = f2bf(acc * inv);
}

// ---------------------------------------------------------------------------
// Fused gi/gh GEMMs + GRU combine (R5-proven). grid (4, 64).
// ---------------------------------------------------------------------------
__global__ __launch_bounds__(256) void gru_gemm_kernel(
    const unsigned short* __restrict__ Au, const unsigned short* __restrict__ As,
    const unsigned short* __restrict__ Wc2, const unsigned short* __restrict__ Whh,
    const float* __restrict__ b_ih, const float* __restrict__ b_hh,
    const float* __restrict__ snf, float* __restrict__ hout) {
  int lane = threadIdx.x & 63, w = threadIdx.x >> 6;
  int lo = lane & 15, hi = lane >> 4;
  int m0 = blockIdx.y << 4;
  int cw = (blockIdx.x << 7) + (w << 5);
  const unsigned short* aup = Au + (size_t)(m0 + lo) * 512 + (hi << 3);
  const unsigned short* asp = As + (size_t)(m0 + lo) * 512 + (hi << 3);
  const unsigned short* bc[2][3];
  const unsigned short* bh[2][3];
#pragma unroll
  for (int jt = 0; jt < 2; ++jt)
#pragma unroll
    for (int gt = 0; gt < 3; ++gt) {
      size_t rowoff = (size_t)(cw + jt * 16 + gt * 512 + lo) * 512 + (hi << 3);
      bc[jt][gt] = Wc2 + rowoff;
      bh[jt][gt] = Whh + rowoff;
    }
  f32x4 gi[2][3], gh[2][3];
#pragma unroll
  for (int jt = 0; jt < 2; ++jt)
#pragma unroll
    for (int gt = 0; gt < 3; ++gt) {
      gi[jt][gt] = f32x4{0.f, 0.f, 0.f, 0.f};
      gh[jt][gt] = f32x4{0.f, 0.f, 0.f, 0.f};
    }
  for (int kk = 0; kk < 512; kk += 32) {
    bf16x8 au = *reinterpret_cast<const bf16x8*>(aup + kk);
    bf16x8 as_ = *reinterpret_cast<const bf16x8*>(asp + kk);
#pragma unroll
    for (int jt = 0; jt < 2; ++jt)
#pragma unroll
      for (int gt = 0; gt < 3; ++gt) {
        bf16x8 wc = *reinterpret_cast<const bf16x8*>(bc[jt][gt] + kk);
        bf16x8 wh = *reinterpret_cast<const bf16x8*>(bh[jt][gt] + kk);
        gi[jt][gt] = __builtin_amdgcn_mfma_f32_16x16x32_bf16(au, wc, gi[jt][gt], 0, 0, 0);
        gh[jt][gt] = __builtin_amdgcn_mfma_f32_16x16x32_bf16(as_, wh, gh[jt][gt], 0, 0, 0);
      }
  }
#pragma unroll
  for (int jt = 0; jt < 2; ++jt) {
    int col = cw + (jt << 4) + lo;
    float bir = b_ih[col], biz = b_ih[col + 512], bin = b_ih[col + 1024];
    float bhr = b_hh[col], bhz = b_hh[col + 512], bhn = b_hh[col + 1024];
#pragma unroll
    for (int r = 0; r < 4; ++r) {
      int row = m0 + (hi << 2) + r;
      float rr = (gi[jt][0][r] + bir) + (gh[jt][0][r] + bhr);
      float zz = (gi[jt][1][r] + biz) + (gh[jt][1][r] + bhz);
      float rg = 1.f / (1.f + __expf(-rr));
      float zg = 1.f / (1.f + __expf(-zz));
      float a = (gi[jt][2][r] + bin) + rg * (gh[jt][2][r] + bhn);
      float ee = __expf(-2.f * fabsf(a));
      float nt = (1.f - ee) / (1.f + ee);
      float n = copysignf(nt, a);
      float hp = snf[(size_t)row * 512 + col];
      hout[(size_t)row * 512 + col] = (1.f - zg) * n + zg * hp;
    }
  }
}

// ---------------------------------------------------------------------------
extern "C" void kernel_launch(void* const* d_in, const int* in_sizes, int n_in,
                              void* d_out, int out_size, void* d_ws, size_t ws_size,
                              hipStream_t stream) {
  const float* slots_in  = (const float*)d_in[0];
  const float* features  = (const float*)d_in[1];
  const float* ln_feat_g = (const float*)d_in[2];
  const float* ln_feat_b = (const float*)d_in[3];
  const float* ln_slot_g = (const float*)d_in[4];
  const float* ln_slot_b = (const float*)d_in[5];
  const float* w_k  = (const float*)d_in[6];
  const float* w_v  = (const float*)d_in[7];
  const float* w_q  = (const float*)d_in[8];
  const float* w_ih = (const float*)d_in[9];
  const float* w_hh = (const float*)d_in[10];
  const float* b_ih = (const float*)d_in[11];
  const float* b_hh = (const float*)d_in[12];
  const float* mlp_ln_g = (const float*)d_in[13];
  const float* mlp_ln_b = (const float*)d_in[14];
  const float* w1 = (const float*)d_in[15];
  const float* b1 = (const float*)d_in[16];
  const float* w2 = (const float*)d_in[17];
  const float* b2 = (const float*)d_in[18];

  char* ws = (char*)d_ws;
  size_t off = 0;
  auto alloc = [&](size_t bytes) {
    char* p = ws + off;
    off += (bytes + 255) & ~(size_t)255;
    return p;
  };
  unsigned short* f_norm  = (unsigned short*)alloc((size_t)64 * 4096 * 512 * 2);  // 256MB
  unsigned short* qp_bf   = (unsigned short*)alloc(1024 * 512 * 2);
  float*          s_n_f   = (float*)alloc(1024 * 512 * 4);
  unsigned short* s_n_bf  = (unsigned short*)alloc(1024 * 512 * 2);
  float*          fsumP   = (float*)alloc(64 * 32 * 16 * 4);
  float*          Upart   = (float*)alloc((size_t)64 * 16 * 16 * 512 * 4);        // 32MB
  unsigned short* updp_bf = (unsigned short*)alloc(1024 * 512 * 2);
  float*          slots_c = (float*)alloc(1024 * 512 * 4);
  unsigned short* hln_bf  = (unsigned short*)alloc(1024 * 512 * 2);
  unsigned short* hm_bf   = (unsigned short*)alloc((size_t)1024 * 2048 * 2);
  unsigned short* Wqk_bf  = (unsigned short*)alloc(512 * 512 * 2);   // wk^T wq
  unsigned short* Wih_bf  = (unsigned short*)alloc(1536 * 512 * 2);
  unsigned short* Whh_bf  = (unsigned short*)alloc(1536 * 512 * 2);
  unsigned short* WkT_bf  = (unsigned short*)alloc(512 * 512 * 2);
  unsigned short* WqT_bf  = (unsigned short*)alloc(512 * 512 * 2);
  unsigned short* WvT_bf  = (unsigned short*)alloc(512 * 512 * 2);
  unsigned short* Wc2_bf  = (unsigned short*)alloc(1536 * 512 * 2);  // wih@wv
  unsigned short* W1_bf   = (unsigned short*)alloc((size_t)2048 * 512 * 2);
  unsigned short* W2_bf   = (unsigned short*)alloc((size_t)512 * 2048 * 2);

  float* out_slots = (float*)d_out;               // [64,16,512]
  float* out_attn  = out_slots + 1024 * 512;      // [64,16,4096]

  // --- setup ---
  prep_weights_kernel<<<dim3(6656), dim3(256), 0, stream>>>(
      w_ih, w_hh, w1, w2, w_k, w_q, w_v,
      Wih_bf, Whh_bf, W1_bf, W2_bf, WkT_bf, WqT_bf, WvT_bf);
  gemm_nt<0><<<dim3(4, 16), dim3(256), 0, stream>>>(
      WkT_bf, WqT_bf, nullptr, Wqk_bf, 512, 512, 512);
  gemm_nt<0><<<dim3(4, 48), dim3(256), 0, stream>>>(
      Wih_bf, WvT_bf, nullptr, Wc2_bf, 1536, 512, 512);
  // f_norm = LN(features) -> bf16 (single pass)
  ln512_kernel<0><<<dim3(65536), dim3(256), 0, stream>>>(
      features, ln_feat_g, ln_feat_b, f_norm, nullptr, 262144);

  for (int it = 0; it < 3; ++it) {
    const float* slots_src = (it == 0) ? slots_in : slots_c;
    // s_n = LN(slots)
    ln512_kernel<1><<<dim3(256), dim3(256), 0, stream>>>(
        slots_src, ln_slot_g, ln_slot_b, s_n_bf, s_n_f, 1024);
    // qp = s_n @ Wqk^T
    gemm_nt64<0><<<dim3(8, 32), dim3(256), 0, stream>>>(
        s_n_bf, Wqk_bf, nullptr, nullptr, nullptr, qp_bf, 1024, 512, 512);
    // fused dots+softmax+PV (single f_norm pass)
    fused_attn_kernel<<<dim3(16, 64), dim3(128), 0, stream>>>(
        qp_bf, f_norm, Upart, fsumP, (it == 2) ? out_attn : nullptr);
    // finalize updates (invf folded in)
    upd_fin_kernel<<<dim3(2048), dim3(256), 0, stream>>>(Upart, fsumP, updp_bf);
    // gi/gh GEMMs + GRU -> slots_c
    gru_gemm_kernel<<<dim3(4, 64), dim3(256), 0, stream>>>(
        updp_bf, s_n_bf, Wc2_bf, Whh_bf, b_ih, b_hh, s_n_f, slots_c);
    // h_ln = LN_mlp(slots_c)
    ln512_kernel<0><<<dim3(256), dim3(256), 0, stream>>>(
        slots_c, mlp_ln_g, mlp_ln_b, hln_bf, nullptr, 1024);
    // MLP (split kernels, full-GPU grids — R5-proven)
    gemm_nt<3><<<dim3(16, 32), dim3(256), 0, stream>>>(
        hln_bf, W1_bf, b1, hm_bf, 1024, 2048, 512);
    float* slot_dst = (it == 2) ? out_slots : slots_c;
    gemm_nt64<4><<<dim3(8, 32), dim3(256), 0, stream>>>(
        hm_bf, W2_bf, b2, slots_c, slot_dst, nullptr, 1024, 512, 2048);
  }
  (void)in_sizes; (void)n_in; (void)out_size; (void)ws_size;
}

// Round 11
// 679.259 us; speedup vs baseline: 1.1119x; 1.0231x over previous
//
#include <hip/hip_runtime.h>

// ---------------------------------------------------------------------------
// SlotAttention forward, MI355X. B=64,S=16,F=4096,D=512,H=2048,3 iters.
// R11: R10 plateau state (694us, confirmed twice) + ONE delta: Upart stored
// as bf16 (was fp32) — halves the fused_attn->upd_fin 64MB/iter round-trip.
// Accuracy: +~0.2% rel on updates', same order as existing updp_bf rounding.
// ---------------------------------------------------------------------------

typedef __bf16 bf16x8 __attribute__((ext_vector_type(8)));
typedef float  f32x4  __attribute__((ext_vector_type(4)));

#define DEV static __device__ __forceinline__

DEV float bf2f_lo(unsigned int u) { union { unsigned int i; float f; } v; v.i = u << 16; return v.f; }
DEV unsigned short f2bf(float f) {
  union { float f; unsigned int i; } v; v.f = f;
  return (unsigned short)((v.i + 0x7FFFu + ((v.i >> 16) & 1u)) >> 16);
}

// ---------------------------------------------------------------------------
// LayerNorm rows of 512 (one wave per row). fp32 in, bf16 out (+opt fp32).
// ---------------------------------------------------------------------------
template<int OUTF>
__global__ __launch_bounds__(256) void ln512_kernel(
    const float* __restrict__ X, const float* __restrict__ g,
    const float* __restrict__ b, unsigned short* __restrict__ Yb,
    float* __restrict__ Yf, int R) {
  int wave = (blockIdx.x << 2) | (threadIdx.x >> 6);
  int lane = threadIdx.x & 63;
  if (wave >= R) return;
  const float4* xp = reinterpret_cast<const float4*>(X + (size_t)wave * 512);
  float4 x0 = xp[lane * 2], x1 = xp[lane * 2 + 1];
  float xv[8] = {x0.x, x0.y, x0.z, x0.w, x1.x, x1.y, x1.z, x1.w};
  float s = 0.f, q = 0.f;
#pragma unroll
  for (int j = 0; j < 8; ++j) { s += xv[j]; q += xv[j] * xv[j]; }
#pragma unroll
  for (int off = 32; off; off >>= 1) { s += __shfl_xor(s, off); q += __shfl_xor(q, off); }
  float mu = s * (1.0f / 512.0f);
  float var = q * (1.0f / 512.0f) - mu * mu;
  float rstd = rsqrtf(var + 1e-5f);
  const float4* gp = reinterpret_cast<const float4*>(g);
  const float4* bp = reinterpret_cast<const float4*>(b);
  float4 g0 = gp[lane * 2], g1 = gp[lane * 2 + 1];
  float4 b0 = bp[lane * 2], b1 = bp[lane * 2 + 1];
  float gv[8] = {g0.x, g0.y, g0.z, g0.w, g1.x, g1.y, g1.z, g1.w};
  float bv[8] = {b0.x, b0.y, b0.z, b0.w, b1.x, b1.y, b1.z, b1.w};
  float y[8];
  unsigned short u[8];
#pragma unroll
  for (int j = 0; j < 8; ++j) { y[j] = (xv[j] - mu) * rstd * gv[j] + bv[j]; u[j] = f2bf(y[j]); }
  uint4 o = make_uint4(
      (unsigned)u[0] | ((unsigned)u[1] << 16), (unsigned)u[2] | ((unsigned)u[3] << 16),
      (unsigned)u[4] | ((unsigned)u[5] << 16), (unsigned)u[6] | ((unsigned)u[7] << 16));
  reinterpret_cast<uint4*>(Yb + (size_t)wave * 512)[lane] = o;
  if (OUTF) {
    float4* yf = reinterpret_cast<float4*>(Yf + (size_t)wave * 512);
    yf[lane * 2]     = make_float4(y[0], y[1], y[2], y[3]);
    yf[lane * 2 + 1] = make_float4(y[4], y[5], y[6], y[7]);
  }
}

// ---------------------------------------------------------------------------
// Merged setup: cvt w_ih/w_hh/w1/w2 + transpose-cvt wk/wq/wv. grid 6656.
// ---------------------------------------------------------------------------
__global__ __launch_bounds__(256) void prep_weights_kernel(
    const float* __restrict__ w_ih, const float* __restrict__ w_hh,
    const float* __restrict__ w1, const float* __restrict__ w2,
    const float* __restrict__ w_k, const float* __restrict__ w_q,
    const float* __restrict__ w_v,
    unsigned short* __restrict__ Wih, unsigned short* __restrict__ Whh,
    unsigned short* __restrict__ W1, unsigned short* __restrict__ W2,
    unsigned short* __restrict__ WkT, unsigned short* __restrict__ WqT,
    unsigned short* __restrict__ WvT) {
  int blk = blockIdx.x, tid = threadIdx.x;
  if (blk < 3584) {  // flat converts (float4 units)
    const float* src; unsigned short* dst; int base;
    if (blk < 768)       { src = w_ih; dst = Wih; base = blk; }
    else if (blk < 1536) { src = w_hh; dst = Whh; base = blk - 768; }
    else if (blk < 2560) { src = w1;   dst = W1;  base = blk - 1536; }
    else                 { src = w2;   dst = W2;  base = blk - 2560; }
    int i = base * 256 + tid;
    float4 v = reinterpret_cast<const float4*>(src)[i];
    unsigned int lo = (unsigned)f2bf(v.x) | ((unsigned)f2bf(v.y) << 16);
    unsigned int hi = (unsigned)f2bf(v.z) | ((unsigned)f2bf(v.w) << 16);
    reinterpret_cast<uint2*>(dst)[i] = make_uint2(lo, hi);
  } else {  // 512x512 transposes
    int rgn = (blk - 3584) >> 10, base = (blk - 3584) & 1023;
    const float* src = rgn == 0 ? w_k : rgn == 1 ? w_q : w_v;
    unsigned short* dst = rgn == 0 ? WkT : rgn == 1 ? WqT : WvT;
    int t2 = base * 256 + tid;
    int i = t2 >> 9, j = t2 & 511;
    dst[t2] = f2bf(src[j * 512 + i]);
  }
}

// ---------------------------------------------------------------------------
// NT bf16 MFMA GEMM, block 32m x 128n, 4 waves n-adjacent, wave 32x32.
// MODE 0: bf16 plain. MODE 3: relu(v+bias)->bf16.
// ---------------------------------------------------------------------------
template<int MODE>
__global__ __launch_bounds__(256) void gemm_nt(
    const unsigned short* __restrict__ A, const unsigned short* __restrict__ Bm,
    const float* __restrict__ bias, unsigned short* __restrict__ Cb,
    int M, int N, int K) {
  int lane = threadIdx.x & 63;
  int w = threadIdx.x >> 6;
  int m0 = blockIdx.y << 5;
  int n0 = (blockIdx.x << 7) + (w << 5);
  int lo = lane & 15, hi = lane >> 4;
  const unsigned short* Ap = A + (size_t)(m0 + lo) * K + (hi << 3);
  const unsigned short* Bp = Bm + (size_t)(n0 + lo) * K + (hi << 3);
  f32x4 acc[2][2];
#pragma unroll
  for (int i = 0; i < 2; ++i)
#pragma unroll
    for (int j = 0; j < 2; ++j) acc[i][j] = f32x4{0.f, 0.f, 0.f, 0.f};
#pragma unroll 2
  for (int kk = 0; kk < K; kk += 32) {
    bf16x8 a0 = *reinterpret_cast<const bf16x8*>(Ap + kk);
    bf16x8 a1 = *reinterpret_cast<const bf16x8*>(Ap + (size_t)16 * K + kk);
    bf16x8 b0 = *reinterpret_cast<const bf16x8*>(Bp + kk);
    bf16x8 b1 = *reinterpret_cast<const bf16x8*>(Bp + (size_t)16 * K + kk);
    acc[0][0] = __builtin_amdgcn_mfma_f32_16x16x32_bf16(a0, b0, acc[0][0], 0, 0, 0);
    acc[0][1] = __builtin_amdgcn_mfma_f32_16x16x32_bf16(a0, b1, acc[0][1], 0, 0, 0);
    acc[1][0] = __builtin_amdgcn_mfma_f32_16x16x32_bf16(a1, b0, acc[1][0], 0, 0, 0);
    acc[1][1] = __builtin_amdgcn_mfma_f32_16x16x32_bf16(a1, b1, acc[1][1], 0, 0, 0);
  }
#pragma unroll
  for (int i = 0; i < 2; ++i)
#pragma unroll
    for (int j = 0; j < 2; ++j) {
      int col = n0 + (j << 4) + lo;
      float bvv = (MODE == 3) ? bias[col] : 0.f;
#pragma unroll
      for (int r = 0; r < 4; ++r) {
        int row = m0 + (i << 4) + (hi << 2) + r;
        float v = acc[i][j][r];
        if (MODE == 0) Cb[(size_t)row * N + col] = f2bf(v);
        else           Cb[(size_t)row * N + col] = f2bf(fmaxf(v + bvv, 0.f));
      }
    }
}

// ---------------------------------------------------------------------------
// NT bf16 GEMM, block 32m x 64n, 4 waves (2m x 2n), wave 16x32.
// MODE 0: bf16 plain. MODE 4: v + bias + res -> f32.
// ---------------------------------------------------------------------------
template<int MODE>
__global__ __launch_bounds__(256) void gemm_nt64(
    const unsigned short* __restrict__ A, const unsigned short* __restrict__ Bm,
    const float* __restrict__ bias, const float* __restrict__ res,
    float* __restrict__ Cf, unsigned short* __restrict__ Cb,
    int M, int N, int K) {
  int lane = threadIdx.x & 63;
  int w = threadIdx.x >> 6;
  int m0 = (blockIdx.y << 5) + ((w >> 1) << 4);
  int n0 = (blockIdx.x << 6) + ((w & 1) << 5);
  int lo = lane & 15, hi = lane >> 4;
  const unsigned short* Ap = A + (size_t)(m0 + lo) * K + (hi << 3);
  const unsigned short* Bp = Bm + (size_t)(n0 + lo) * K + (hi << 3);
  f32x4 acc[2];
  acc[0] = f32x4{0.f, 0.f, 0.f, 0.f};
  acc[1] = f32x4{0.f, 0.f, 0.f, 0.f};
#pragma unroll 2
  for (int kk = 0; kk < K; kk += 32) {
    bf16x8 a0 = *reinterpret_cast<const bf16x8*>(Ap + kk);
    bf16x8 b0 = *reinterpret_cast<const bf16x8*>(Bp + kk);
    bf16x8 b1 = *reinterpret_cast<const bf16x8*>(Bp + (size_t)16 * K + kk);
    acc[0] = __builtin_amdgcn_mfma_f32_16x16x32_bf16(a0, b0, acc[0], 0, 0, 0);
    acc[1] = __builtin_amdgcn_mfma_f32_16x16x32_bf16(a0, b1, acc[1], 0, 0, 0);
  }
#pragma unroll
  for (int j = 0; j < 2; ++j) {
    int col = n0 + (j << 4) + lo;
    float bvv = (MODE == 4) ? bias[col] : 0.f;
#pragma unroll
    for (int r = 0; r < 4; ++r) {
      int row = m0 + (hi << 2) + r;
      float v = acc[j][r];
      if (MODE == 0) Cb[(size_t)row * N + col] = f2bf(v);
      else Cf[(size_t)row * N + col] = v + bvv + res[(size_t)row * N + col];
    }
  }
}

// ---------------------------------------------------------------------------
// Fused attention (R5-proven, 128 thr / 2 waves): per block (b, 256-f group),
// loop 8 chunks of 32 f: stage f_norm[32f][512d] in LDS (row stride 514 u16),
// dots MFMA -> softmax over s (shfl) -> attn to LDS -> PV MFMA accumulate.
// R11: Upart written as bf16 (halves round-trip traffic).
// ---------------------------------------------------------------------------
__global__ __launch_bounds__(128) void fused_attn_kernel(
    const unsigned short* __restrict__ Qp,   // [B,16,512] bf16
    const unsigned short* __restrict__ Fn,   // [B,4096,512] bf16
    unsigned short* __restrict__ Upart,      // [B,16,16,512] bf16
    float* __restrict__ fsumP,               // [B,32,16]
    float* __restrict__ attn_out) {          // [B,16,4096] fp32 or null
  __shared__ unsigned short tile[32 * 514];     // 32896 B
  __shared__ unsigned short attn_lds[16 * 34];  // 1088 B
  int b = blockIdx.y, g = blockIdx.x;
  int t = threadIdx.x;
  int w = t >> 6, lane = t & 63;
  int lo = lane & 15, hi = lane >> 4;
  unsigned int* tile32 = reinterpret_cast<unsigned int*>(tile);

  const unsigned short* qa = Qp + ((size_t)b * 16 + lo) * 512 + (hi << 3);
  const unsigned short* gstage = Fn + ((size_t)b * 4096 + g * 256) * 512;

  f32x4 uacc[16];
#pragma unroll
  for (int s = 0; s < 16; ++s) uacc[s] = f32x4{0.f, 0.f, 0.f, 0.f};
  float fs[4] = {0.f, 0.f, 0.f, 0.f};

  const float scale = 0.04419417382415922f;  // 512^-0.5

  {
    uint4 nx[16];
#pragma unroll
    for (int k = 0; k < 16; ++k)
      nx[k] = *reinterpret_cast<const uint4*>(gstage + (size_t)t * 8 + k * 1024);
#pragma unroll
    for (int k = 0; k < 16; ++k) {
      unsigned int* p32 = tile32 + (k * 2 + w) * 257 + lane * 4;
      p32[0] = nx[k].x; p32[1] = nx[k].y; p32[2] = nx[k].z; p32[3] = nx[k].w;
    }
  }
  __syncthreads();

  for (int c = 0; c < 8; ++c) {
    uint4 nx[16];
    if (c < 7) {
      const unsigned short* src = gstage + (size_t)(c + 1) * 16384;
#pragma unroll
      for (int k = 0; k < 16; ++k)
        nx[k] = *reinterpret_cast<const uint4*>(src + (size_t)t * 8 + k * 1024);
    }
    // --- dots ---
    f32x4 dacc = {0.f, 0.f, 0.f, 0.f};
#pragma unroll
    for (int ks = 0; ks < 16; ++ks) {
      const unsigned int* bp32 = tile32 + (w * 16 + lo) * 257 + ks * 16 + (hi << 2);
      union { unsigned int u[4]; bf16x8 v; } bf;
      bf.u[0] = bp32[0]; bf.u[1] = bp32[1]; bf.u[2] = bp32[2]; bf.u[3] = bp32[3];
      bf16x8 a = *reinterpret_cast<const bf16x8*>(qa + ks * 32);
      dacc = __builtin_amdgcn_mfma_f32_16x16x32_bf16(a, bf.v, dacc, 0, 0, 0);
    }
    // --- softmax over s ---
    float d4[4], mx = -3.4e38f;
#pragma unroll
    for (int r = 0; r < 4; ++r) { d4[r] = dacc[r] * scale; mx = fmaxf(mx, d4[r]); }
    mx = fmaxf(mx, __shfl_xor(mx, 16));
    mx = fmaxf(mx, __shfl_xor(mx, 32));
    float e4[4], ss = 0.f;
#pragma unroll
    for (int r = 0; r < 4; ++r) { e4[r] = __expf(d4[r] - mx); ss += e4[r]; }
    ss += __shfl_xor(ss, 16);
    ss += __shfl_xor(ss, 32);
    float inv = 1.f / ss;
    float cs[4];
#pragma unroll
    for (int r = 0; r < 4; ++r) {
      float p = e4[r] * inv;  // pre_norm_attn
      if (attn_out)
        attn_out[((size_t)b * 16 + (hi << 2) + r) * 4096 + g * 256 + c * 32 + (w << 4) + lo] = p;
      unsigned short uu = f2bf(p + 1e-8f);
      attn_lds[((hi << 2) + r) * 34 + (w << 4) + lo] = uu;
      cs[r] = bf2f_lo(uu);  // rounded -> consistent fsum
    }
#pragma unroll
    for (int m = 1; m < 16; m <<= 1) {
#pragma unroll
      for (int r = 0; r < 4; ++r) cs[r] += __shfl_xor(cs[r], m);
    }
#pragma unroll
    for (int r = 0; r < 4; ++r) fs[r] += cs[r];  // valid on lo==0 lanes
    __syncthreads();
    // --- PV ---
    {
      const unsigned int* ap32 = reinterpret_cast<const unsigned int*>(attn_lds) + lo * 17 + (hi << 2);
      union { unsigned int u[4]; bf16x8 v; } paf;
      paf.u[0] = ap32[0]; paf.u[1] = ap32[1]; paf.u[2] = ap32[2]; paf.u[3] = ap32[3];
#pragma unroll
      for (int sub = 0; sub < 16; ++sub) {
        int dcol = (w << 8) + (sub << 4) + lo;
        union { unsigned short u[8]; bf16x8 v; } pbf;
#pragma unroll
        for (int j = 0; j < 8; ++j)
          pbf.u[j] = tile[((hi << 3) + j) * 514 + dcol];
        uacc[sub] = __builtin_amdgcn_mfma_f32_16x16x32_bf16(paf.v, pbf.v, uacc[sub], 0, 0, 0);
      }
    }
    __syncthreads();
    if (c < 7) {
#pragma unroll
      for (int k = 0; k < 16; ++k) {
        unsigned int* p32 = tile32 + (k * 2 + w) * 257 + lane * 4;
        p32[0] = nx[k].x; p32[1] = nx[k].y; p32[2] = nx[k].z; p32[3] = nx[k].w;
      }
      __syncthreads();
    }
  }
#pragma unroll
  for (int sub = 0; sub < 16; ++sub) {
#pragma unroll
    for (int r = 0; r < 4; ++r)
      Upart[((size_t)(b * 16 + g) * 16 + (hi << 2) + r) * 512 + (w << 8) + (sub << 4) + lo] =
          f2bf(uacc[sub][r]);
  }
  if (lo == 0) {
#pragma unroll
    for (int r = 0; r < 4; ++r)
      fsumP[((size_t)(b * 16 + g) * 2 + w) * 16 + (hi << 2) + r] = fs[r];
  }
}

// ---------------------------------------------------------------------------
// finalize: upd_bf[b,s,d] = f2bf( (sum_g Upart[b,g,s,d]) / (sum fsumP[b,:,s]) )
// grid 2048: block = one (b,s,d-half). Upart bf16 (R11). invf redundant.
// ---------------------------------------------------------------------------
__global__ __launch_bounds__(256) void upd_fin_kernel(
    const unsigned short* __restrict__ Upart, const float* __restrict__ fsumP,
    unsigned short* __restrict__ outb) {
  int blk = blockIdx.x;
  int b = blk >> 5;
  int s = (blk >> 1) & 15;
  int d = ((blk & 1) << 8) + threadIdx.x;
  float fsum = 0.f;
#pragma unroll
  for (int i = 0; i < 32; ++i) fsum += fsumP[(size_t)b * 512 + i * 16 + s];
  float inv = 1.f / fsum;
  const unsigned short* p = Upart + (size_t)b * 131072 + s * 512 + d;
  float acc = 0.f;
#pragma unroll
  for (int g = 0; g < 16; ++g) acc += bf2f_lo((unsigned)p[(size_t)g * 8192]);
  outb[((size_t)b * 16 + s) * 512 + d] = f2bf(acc * inv);
}

// ---------------------------------------------------------------------------
// Fused gi/gh GEMMs + GRU combine (R5-proven). grid (4, 64).
// ---------------------------------------------------------------------------
__global__ __launch_bounds__(256) void gru_gemm_kernel(
    const unsigned short* __restrict__ Au, const unsigned short* __restrict__ As,
    const unsigned short* __restrict__ Wc2, const unsigned short* __restrict__ Whh,
    const float* __restrict__ b_ih, const float* __restrict__ b_hh,
    const float* __restrict__ snf, float* __restrict__ hout) {
  int lane = threadIdx.x & 63, w = threadIdx.x >> 6;
  int lo = lane & 15, hi = lane >> 4;
  int m0 = blockIdx.y << 4;
  int cw = (blockIdx.x << 7) + (w << 5);
  const unsigned short* aup = Au + (size_t)(m0 + lo) * 512 + (hi << 3);
  const unsigned short* asp = As + (size_t)(m0 + lo) * 512 + (hi << 3);
  const unsigned short* bc[2][3];
  const unsigned short* bh[2][3];
#pragma unroll
  for (int jt = 0; jt < 2; ++jt)
#pragma unroll
    for (int gt = 0; gt < 3; ++gt) {
      size_t rowoff = (size_t)(cw + jt * 16 + gt * 512 + lo) * 512 + (hi << 3);
      bc[jt][gt] = Wc2 + rowoff;
      bh[jt][gt] = Whh + rowoff;
    }
  f32x4 gi[2][3], gh[2][3];
#pragma unroll
  for (int jt = 0; jt < 2; ++jt)
#pragma unroll
    for (int gt = 0; gt < 3; ++gt) {
      gi[jt][gt] = f32x4{0.f, 0.f, 0.f, 0.f};
      gh[jt][gt] = f32x4{0.f, 0.f, 0.f, 0.f};
    }
  for (int kk = 0; kk < 512; kk += 32) {
    bf16x8 au = *reinterpret_cast<const bf16x8*>(aup + kk);
    bf16x8 as_ = *reinterpret_cast<const bf16x8*>(asp + kk);
#pragma unroll
    for (int jt = 0; jt < 2; ++jt)
#pragma unroll
      for (int gt = 0; gt < 3; ++gt) {
        bf16x8 wc = *reinterpret_cast<const bf16x8*>(bc[jt][gt] + kk);
        bf16x8 wh = *reinterpret_cast<const bf16x8*>(bh[jt][gt] + kk);
        gi[jt][gt] = __builtin_amdgcn_mfma_f32_16x16x32_bf16(au, wc, gi[jt][gt], 0, 0, 0);
        gh[jt][gt] = __builtin_amdgcn_mfma_f32_16x16x32_bf16(as_, wh, gh[jt][gt], 0, 0, 0);
      }
  }
#pragma unroll
  for (int jt = 0; jt < 2; ++jt) {
    int col = cw + (jt << 4) + lo;
    float bir = b_ih[col], biz = b_ih[col + 512], bin = b_ih[col + 1024];
    float bhr = b_hh[col], bhz = b_hh[col + 512], bhn = b_hh[col + 1024];
#pragma unroll
    for (int r = 0; r < 4; ++r) {
      int row = m0 + (hi << 2) + r;
      float rr = (gi[jt][0][r] + bir) + (gh[jt][0][r] + bhr);
      float zz = (gi[jt][1][r] + biz) + (gh[jt][1][r] + bhz);
      float rg = 1.f / (1.f + __expf(-rr));
      float zg = 1.f / (1.f + __expf(-zz));
      float a = (gi[jt][2][r] + bin) + rg * (gh[jt][2][r] + bhn);
      float ee = __expf(-2.f * fabsf(a));
      float nt = (1.f - ee) / (1.f + ee);
      float n = copysignf(nt, a);
      float hp = snf[(size_t)row * 512 + col];
      hout[(size_t)row * 512 + col] = (1.f - zg) * n + zg * hp;
    }
  }
}

// ---------------------------------------------------------------------------
extern "C" void kernel_launch(void* const* d_in, const int* in_sizes, int n_in,
                              void* d_out, int out_size, void* d_ws, size_t ws_size,
                              hipStream_t stream) {
  const float* slots_in  = (const float*)d_in[0];
  const float* features  = (const float*)d_in[1];
  const float* ln_feat_g = (const float*)d_in[2];
  const float* ln_feat_b = (const float*)d_in[3];
  const float* ln_slot_g = (const float*)d_in[4];
  const float* ln_slot_b = (const float*)d_in[5];
  const float* w_k  = (const float*)d_in[6];
  const float* w_v  = (const float*)d_in[7];
  const float* w_q  = (const float*)d_in[8];
  const float* w_ih = (const float*)d_in[9];
  const float* w_hh = (const float*)d_in[10];
  const float* b_ih = (const float*)d_in[11];
  const float* b_hh = (const float*)d_in[12];
  const float* mlp_ln_g = (const float*)d_in[13];
  const float* mlp_ln_b = (const float*)d_in[14];
  const float* w1 = (const float*)d_in[15];
  const float* b1 = (const float*)d_in[16];
  const float* w2 = (const float*)d_in[17];
  const float* b2 = (const float*)d_in[18];

  char* ws = (char*)d_ws;
  size_t off = 0;
  auto alloc = [&](size_t bytes) {
    char* p = ws + off;
    off += (bytes + 255) & ~(size_t)255;
    return p;
  };
  unsigned short* f_norm  = (unsigned short*)alloc((size_t)64 * 4096 * 512 * 2);  // 256MB
  unsigned short* qp_bf   = (unsigned short*)alloc(1024 * 512 * 2);
  float*          s_n_f   = (float*)alloc(1024 * 512 * 4);
  unsigned short* s_n_bf  = (unsigned short*)alloc(1024 * 512 * 2);
  float*          fsumP   = (float*)alloc(64 * 32 * 16 * 4);
  unsigned short* Upart   = (unsigned short*)alloc((size_t)64 * 16 * 16 * 512 * 2);  // 16MB bf16
  unsigned short* updp_bf = (unsigned short*)alloc(1024 * 512 * 2);
  float*          slots_c = (float*)alloc(1024 * 512 * 4);
  unsigned short* hln_bf  = (unsigned short*)alloc(1024 * 512 * 2);
  unsigned short* hm_bf   = (unsigned short*)alloc((size_t)1024 * 2048 * 2);
  unsigned short* Wqk_bf  = (unsigned short*)alloc(512 * 512 * 2);   // wk^T wq
  unsigned short* Wih_bf  = (unsigned short*)alloc(1536 * 512 * 2);
  unsigned short* Whh_bf  = (unsigned short*)alloc(1536 * 512 * 2);
  unsigned short* WkT_bf  = (unsigned short*)alloc(512 * 512 * 2);
  unsigned short* WqT_bf  = (unsigned short*)alloc(512 * 512 * 2);
  unsigned short* WvT_bf  = (unsigned short*)alloc(512 * 512 * 2);
  unsigned short* Wc2_bf  = (unsigned short*)alloc(1536 * 512 * 2);  // wih@wv
  unsigned short* W1_bf   = (unsigned short*)alloc((size_t)2048 * 512 * 2);
  unsigned short* W2_bf   = (unsigned short*)alloc((size_t)512 * 2048 * 2);

  float* out_slots = (float*)d_out;               // [64,16,512]
  float* out_attn  = out_slots + 1024 * 512;      // [64,16,4096]

  // --- setup ---
  prep_weights_kernel<<<dim3(6656), dim3(256), 0, stream>>>(
      w_ih, w_hh, w1, w2, w_k, w_q, w_v,
      Wih_bf, Whh_bf, W1_bf, W2_bf, WkT_bf, WqT_bf, WvT_bf);
  gemm_nt<0><<<dim3(4, 16), dim3(256), 0, stream>>>(
      WkT_bf, WqT_bf, nullptr, Wqk_bf, 512, 512, 512);
  gemm_nt<0><<<dim3(4, 48), dim3(256), 0, stream>>>(
      Wih_bf, WvT_bf, nullptr, Wc2_bf, 1536, 512, 512);
  // f_norm = LN(features) -> bf16 (single pass)
  ln512_kernel<0><<<dim3(65536), dim3(256), 0, stream>>>(
      features, ln_feat_g, ln_feat_b, f_norm, nullptr, 262144);

  for (int it = 0; it < 3; ++it) {
    const float* slots_src = (it == 0) ? slots_in : slots_c;
    // s_n = LN(slots)
    ln512_kernel<1><<<dim3(256), dim3(256), 0, stream>>>(
        slots_src, ln_slot_g, ln_slot_b, s_n_bf, s_n_f, 1024);
    // qp = s_n @ Wqk^T
    gemm_nt64<0><<<dim3(8, 32), dim3(256), 0, stream>>>(
        s_n_bf, Wqk_bf, nullptr, nullptr, nullptr, qp_bf, 1024, 512, 512);
    // fused dots+softmax+PV (single f_norm pass)
    fused_attn_kernel<<<dim3(16, 64), dim3(128), 0, stream>>>(
        qp_bf, f_norm, Upart, fsumP, (it == 2) ? out_attn : nullptr);
    // finalize updates (invf folded in)
    upd_fin_kernel<<<dim3(2048), dim3(256), 0, stream>>>(Upart, fsumP, updp_bf);
    // gi/gh GEMMs + GRU -> slots_c
    gru_gemm_kernel<<<dim3(4, 64), dim3(256), 0, stream>>>(
        updp_bf, s_n_bf, Wc2_bf, Whh_bf, b_ih, b_hh, s_n_f, slots_c);
    // h_ln = LN_mlp(slots_c)
    ln512_kernel<0><<<dim3(256), dim3(256), 0, stream>>>(
        slots_c, mlp_ln_g, mlp_ln_b, hln_bf, nullptr, 1024);
    // MLP (split kernels, full-GPU grids — R5-proven)
    gemm_nt<3><<<dim3(16, 32), dim3(256), 0, stream>>>(
        hln_bf, W1_bf, b1, hm_bf, 1024, 2048, 512);
    float* slot_dst = (it == 2) ? out_slots : slots_c;
    gemm_nt64<4><<<dim3(8, 32), dim3(256), 0, stream>>>(
        hm_bf, W2_bf, b2, slots_c, slot_dst, nullptr, 1024, 512, 2048);
  }
  (void)in_sizes; (void)n_in; (void)out_size; (void)ws_size;
}